// Round 4
// baseline (1009.913 us; speedup 1.0000x reference)
//
#include <hip/hip_runtime.h>
#include <math.h>

#define NNODE 2048
#define MCLUS 2048
#define KNBR  32
#define CDIM  256
#define HHEAD 8

__device__ __forceinline__ float sigf(float x) { return 1.0f / (1.0f + __expf(-x)); }

__device__ __forceinline__ unsigned short f2bf(float f) {
    unsigned x = __float_as_uint(f);
    unsigned r = ((x >> 16) & 1u) + 0x7FFFu;
    return (unsigned short)((x + r) >> 16);
}
__device__ __forceinline__ float bf2f(unsigned short u) {
    return __uint_as_float(((unsigned)u) << 16);
}
__device__ __forceinline__ float bfld_nt(const unsigned short* p) {
    return bf2f(__builtin_nontemporal_load(p));
}

// ---------------- K0: detect attn_mask storage layout ----------------
__global__ void k0_detect(const unsigned int* __restrict__ mw, int* __restrict__ flag) {
    int i = blockIdx.x * blockDim.x + threadIdx.x;
    unsigned int w = mw[i];
    int vb = (w != 0u && w != 1u && w != 0x3F800000u) ? 1 : 0;
    int vf = (w == 0x3F800000u) ? 1 : 0;
    unsigned long long bal_b = __ballot(vb);
    unsigned long long bal_f = __ballot(vf);
    if ((threadIdx.x & 63) == 0) {
        if (bal_b) atomicOr(flag, 1);
        if (bal_f) atomicOr(flag, 2);
    }
}

__device__ __forceinline__ bool edge_masked(const void* mp, int mode, int e) {
    if (mode & 2) return ((const float*)mp)[e] != 0.0f;
    if (mode & 1) return ((const unsigned char*)mp)[e] != 0;
    return ((const int*)mp)[e] != 0;
}

// ---------------- Kconv: clus fp32 -> bf16 copy ----------------
__global__ __launch_bounds__(256) void kconv(const float* __restrict__ clus,
                                             unsigned short* __restrict__ clh) {
    size_t base = (size_t)blockIdx.x * 2304;
    int t = threadIdx.x;
#pragma unroll
    for (int r = 0; r < 9; ++r) {
        int o = r * 256 + t;
        clh[base + o] = f2bf(clus[base + o]);
    }
}

// ---------------- Kpre: fold tgt/cl_scal parts of radial layer-1 ----------------
__global__ __launch_bounds__(256) void kpre(
    const float* __restrict__ tgt_emb, const float* __restrict__ clus,
    const float* __restrict__ rm0_w1, const float* __restrict__ rv_w1,
    float* __restrict__ TA, float* __restrict__ CA)
{
    int b = blockIdx.x, t = threadIdx.x;
    int slot = t & 31, j = slot & 15, mlp = slot >> 4;
    const float* w1 = mlp ? rv_w1 : rm0_w1;
    if (b < 32) {
        int a = b * 8 + (t >> 5);
        const float* x = tgt_emb + (size_t)a * 128;
        const float* w = w1 + j * 416 + 32;
        float acc = 0.0f;
        for (int i = 0; i < 128; i += 4)
            acc = fmaf(x[i], w[i], fmaf(x[i+1], w[i+1], fmaf(x[i+2], w[i+2], fmaf(x[i+3], w[i+3], acc))));
        TA[a * 32 + slot] = acc;
    } else {
        int m = (b - 32) * 8 + (t >> 5);
        const float* x = clus + (size_t)m * 2304;
        const float* w = w1 + j * 416 + 160;
        float acc = 0.0f;
        for (int i = 0; i < 256; i += 4)
            acc = fmaf(x[i], w[i], fmaf(x[i+1], w[i+1], fmaf(x[i+2], w[i+2], fmaf(x[i+3], w[i+3], acc))));
        CA[m * 32 + slot] = acc;
    }
}

// ---------------- K1: so3_linear; q (fp32) for nodes, key (bf16) for clusters ----
__global__ __launch_bounds__(256) void k1_so3qk(
    const float* __restrict__ nodei, const float* __restrict__ clus,
    const float* __restrict__ W_dot, const float* __restrict__ b_dot,
    float* __restrict__ q_ws, unsigned short* __restrict__ keyh)
{
    __shared__ __align__(16) float X[32][256];
    __shared__ int rx[32], rmm[32];
    int b = blockIdx.x, t = threadIdx.x;
    int l, vr0, nm, moff;
    if (b < 128)      { l = 0; vr0 = b * 32;         nm = 1; moff = 0; }
    else if (b < 512) { l = 1; vr0 = (b - 128) * 32; nm = 3; moff = 1; }
    else              { l = 2; vr0 = (b - 512) * 32; nm = 5; moff = 4; }
    if (t < 32) {
        int vr = vr0 + t;
        rx[t] = vr / nm;
        rmm[t] = moff + vr % nm;
    }
    __syncthreads();
    for (int e = t; e < 32 * 256; e += 256) {
        int r = e >> 8, c = e & 255;
        int x = rx[r], m = rmm[r];
        const float* src = (x < NNODE) ? (nodei + ((size_t)x * 9 + m) * 256)
                                       : (clus + ((size_t)(x - NNODE) * 9 + m) * 256);
        X[r][c] = src[c];
    }
    __syncthreads();
    int d = t & 31, rg = t >> 5;
    int r0 = rg * 4;
    const float4* wrow = (const float4*)(W_dot + ((size_t)l * 32 + d) * 256);
    float acc[4];
    float bd = (l == 0) ? b_dot[d] : 0.0f;
#pragma unroll
    for (int jj = 0; jj < 4; ++jj) acc[jj] = bd;
    for (int c4 = 0; c4 < 64; ++c4) {
        float4 w = wrow[c4];
#pragma unroll
        for (int jj = 0; jj < 4; ++jj) {
            float4 x4 = *(const float4*)&X[r0 + jj][c4 * 4];
            acc[jj] = fmaf(x4.x, w.x, fmaf(x4.y, w.y, fmaf(x4.z, w.z, fmaf(x4.w, w.w, acc[jj]))));
        }
    }
#pragma unroll
    for (int jj = 0; jj < 4; ++jj) {
        int r = r0 + jj;
        int x = rx[r], m = rmm[r];
        if (x < NNODE) q_ws[((size_t)x * 9 + m) * 32 + d] = acc[jj];
        else           keyh[((size_t)(x - NNODE) * 9 + m) * 32 + d] = f2bf(acc[jj]);
    }
}

// ---------------- K2: fully fused per-node pipeline (+final so3) ----------------
__device__ __forceinline__ float lnsilu16(float x, float g, float b) {
    float s = x;
#pragma unroll
    for (int m = 1; m < 16; m <<= 1) s += __shfl_xor(s, m, 16);
    float mu = s * 0.0625f;
    float d = x - mu;
    float s2 = d * d;
#pragma unroll
    for (int m = 1; m < 16; m <<= 1) s2 += __shfl_xor(s2, m, 16);
    float y = d * rsqrtf(s2 * 0.0625f + 1e-5f) * g + b;
    return y * sigf(y);
}

__global__ __launch_bounds__(256, 4) void k2_fused(
    const float* __restrict__ attn_weight, const void* __restrict__ mask,
    const int* __restrict__ mflag,
    const int* __restrict__ f_idx, const float* __restrict__ edge_vec,
    const int* __restrict__ atom_num, const unsigned short* __restrict__ clh,
    const float* __restrict__ q_ws, const unsigned short* __restrict__ keyh,
    const float* __restrict__ TA, const float* __restrict__ CA,
    const float* __restrict__ rm0_w1, const float* __restrict__ rm0_b1,
    const float* __restrict__ rm0_g1, const float* __restrict__ rm0_be1,
    const float* __restrict__ rm0_w2, const float* __restrict__ rm0_b2,
    const float* __restrict__ rm0_g2, const float* __restrict__ rm0_be2,
    const float* __restrict__ rm0_w3, const float* __restrict__ rm0_b3,
    const float* __restrict__ fcw, const float* __restrict__ fcb,
    const float* __restrict__ an_g, const float* __restrict__ an_b,
    const float* __restrict__ alpha_dot,
    const float* __restrict__ rv_w1, const float* __restrict__ rv_b1,
    const float* __restrict__ rv_g1, const float* __restrict__ rv_be1,
    const float* __restrict__ rv_w2, const float* __restrict__ rv_b2,
    const float* __restrict__ rv_g2, const float* __restrict__ rv_be2,
    const float* __restrict__ rv_w3, const float* __restrict__ rv_b3,
    const float* __restrict__ wz, const float* __restrict__ bz,
    float* __restrict__ outfin)
{
    __shared__ float qn[288];
    __shared__ float Ts[32];
    __shared__ float shS[32][9];
    __shared__ float awS[32][32];
    __shared__ float caS[32][32];
    __shared__ __align__(16) float poolS[32 * 196];   // mwaS phase A/B; outS phase C/D
    __shared__ float h2vS[32][17];
    __shared__ float lgS[32][8];
    __shared__ float alS[32][8];
    __shared__ float mxS[8], invS[8];
    __shared__ int idxk[32], maskk[32];

    float (*mwaS)[196] = (float(*)[196])poolS;
    float (*outS)[256] = (float(*)[256])poolS;

    int n = blockIdx.x, t = threadIdx.x;
    int mode = mflag[0];

    for (int i = t; i < 288; i += 256) qn[i] = q_ws[(size_t)n * 288 + i];
    if (t < 32) {
        int an = atom_num[n];
        Ts[t] = TA[an * 32 + t];
        int e = n * KNBR + t;
        idxk[t] = f_idx[e];
        maskk[t] = edge_masked(mask, mode, e) ? 1 : 0;
        float vx = edge_vec[(size_t)e * 3 + 0];
        float vy = edge_vec[(size_t)e * 3 + 1];
        float vz = edge_vec[(size_t)e * 3 + 2];
        float inv = 1.0f / (sqrtf(vx * vx + vy * vy + vz * vz) + 1e-12f);
        float x = vx * inv, y = vy * inv, z = vz * inv;
        shS[t][0] = 0.28209479177387814f;
        shS[t][1] = 0.4886025119029199f * y;
        shS[t][2] = 0.4886025119029199f * z;
        shS[t][3] = 0.4886025119029199f * x;
        shS[t][4] = 1.0925484305920792f * x * y;
        shS[t][5] = 1.0925484305920792f * y * z;
        shS[t][6] = 0.31539156525252005f * (3.0f * z * z - 1.0f);
        shS[t][7] = 1.0925484305920792f * x * z;
        shS[t][8] = 0.5462742152960396f * (x * x - y * y);
    }
    __syncthreads();
    for (int e2 = t; e2 < 1024; e2 += 256) {
        int ek = e2 >> 5, i = e2 & 31;
        awS[ek][i] = maskk[ek] ? 0.0f : attn_weight[((size_t)(n * KNBR + ek)) * 32 + i];
        caS[ek][i] = CA[(size_t)idxk[ek] * 32 + i];
    }
    __syncthreads();

    // ================= phase A: edge MLPs (wave-parallel, 16-lane groups) =========
    {
        int g = t >> 4, j = t & 15;
        for (int ee = 0; ee < 2; ++ee) {
            int e = g + ee * 16;
            int idx = idxk[e];
            float accm = rm0_b1[j] + Ts[j] + caS[e][j];
            float accv = rv_b1[j] + Ts[16 + j] + caS[e][16 + j];
            const float* w1m = rm0_w1 + j * 416;
            const float* w1v = rv_w1 + j * 416;
#pragma unroll
            for (int i = 0; i < 32; i += 4) {
                float a0 = awS[e][i], a1 = awS[e][i + 1], a2 = awS[e][i + 2], a3 = awS[e][i + 3];
                accm = fmaf(a0, w1m[i], fmaf(a1, w1m[i+1], fmaf(a2, w1m[i+2], fmaf(a3, w1m[i+3], accm))));
                accv = fmaf(a0, w1v[i], fmaf(a1, w1v[i+1], fmaf(a2, w1v[i+2], fmaf(a3, w1v[i+3], accv))));
            }
            float hm = lnsilu16(accm, rm0_g1[j], rm0_be1[j]);
            float hv = lnsilu16(accv, rv_g1[j], rv_be1[j]);
            float am2 = rm0_b2[j], av2 = rv_b2[j];
#pragma unroll
            for (int i = 0; i < 16; ++i) {
                am2 = fmaf(__shfl(hm, i, 16), rm0_w2[j * 16 + i], am2);
                av2 = fmaf(__shfl(hv, i, 16), rv_w2[j * 16 + i], av2);
            }
            float h2m = lnsilu16(am2, rm0_g2[j], rm0_be2[j]);
            float h2v = lnsilu16(av2, rv_g2[j], rv_be2[j]);
            h2vS[e][j] = h2v;

            const unsigned short* keyrow = keyh + (size_t)idx * 288;
            float h16[16];
#pragma unroll
            for (int i = 0; i < 16; ++i) h16[i] = __shfl(h2m, i, 16);
#pragma unroll
            for (int r = 0; r < 12; ++r) {
                int d = r * 16 + j;
                const float* w3 = rm0_w3 + d * 16;
                float ew = rm0_b3[d];
#pragma unroll
                for (int i = 0; i < 16; ++i) ew = fmaf(h16[i], w3[i], ew);
                int c = ((r & 1) << 4) + j;   // d & 31
                int bb = r >> 1;              // d >> 5
                float m0v;
                if (bb == 0)      m0v = qn[c] * shS[e][0];
                else if (bb == 1) m0v = qn[32 + c] * shS[e][1] + qn[64 + c] * shS[e][2]
                                      + qn[96 + c] * shS[e][3];
                else if (bb == 2) m0v = qn[128 + c] * shS[e][4] + qn[160 + c] * shS[e][5]
                                      + qn[192 + c] * shS[e][6] + qn[224 + c] * shS[e][7]
                                      + qn[256 + c] * shS[e][8];
                else if (bb == 3) m0v = bf2f(keyrow[c]) * shS[e][0];
                else if (bb == 4) m0v = bf2f(keyrow[32 + c]) * shS[e][1]
                                      + bf2f(keyrow[64 + c]) * shS[e][2]
                                      + bf2f(keyrow[96 + c]) * shS[e][3];
                else              m0v = bf2f(keyrow[128 + c]) * shS[e][4]
                                      + bf2f(keyrow[160 + c]) * shS[e][5]
                                      + bf2f(keyrow[192 + c]) * shS[e][6]
                                      + bf2f(keyrow[224 + c]) * shS[e][7]
                                      + bf2f(keyrow[256 + c]) * shS[e][8];
                mwaS[e][d] = ew * m0v;
            }
        }
    }
    __syncthreads();

    // ================= phase B: af GEMM + LN + smooth_leaky + logits ==============
    {
        int h = t >> 5, s = t & 31;
        float ang = an_g[s], anb = an_b[s], ad = alpha_dot[h * 32 + s];
        float bias = fcb[t];
        const float4* fr = (const float4*)(fcw + (size_t)t * 192);
#pragma unroll
        for (int chunk = 0; chunk < 2; ++chunk) {
            float acc[16];
#pragma unroll
            for (int e = 0; e < 16; ++e) acc[e] = bias;
            for (int i4 = 0; i4 < 48; ++i4) {
                float4 wv = fr[i4];
#pragma unroll
                for (int e = 0; e < 16; ++e) {
                    float4 m4 = *(const float4*)&mwaS[chunk * 16 + e][i4 * 4];
                    acc[e] = fmaf(m4.x, wv.x, fmaf(m4.y, wv.y, fmaf(m4.z, wv.z, fmaf(m4.w, wv.w, acc[e]))));
                }
            }
#pragma unroll
            for (int ee = 0; ee < 16; ++ee) {
                int e = chunk * 16 + ee;
                float v = acc[ee];
                float su = v;
#pragma unroll
                for (int m = 1; m < 32; m <<= 1) su += __shfl_xor(su, m, 32);
                float mu = su * (1.0f / 32.0f);
                float dd = v - mu;
                float s2 = dd * dd;
#pragma unroll
                for (int m = 1; m < 32; m <<= 1) s2 += __shfl_xor(s2, m, 32);
                float rs = rsqrtf(s2 * (1.0f / 32.0f) + 1e-5f);
                float y = dd * rs * ang + anb;
                float sl = 0.6f * y + 0.4f * y * (2.0f * sigf(y) - 1.0f);
                float lgv = sl * ad;
#pragma unroll
                for (int m = 1; m < 32; m <<= 1) lgv += __shfl_xor(lgv, m, 32);
                if (s == 0) lgS[e][h] = maskk[e] ? -1e9f : lgv;
            }
        }
    }
    __syncthreads();

    // ================= softmax over k ============================================
    if (t < 8) {
        float mx = -1e30f;
#pragma unroll
        for (int k = 0; k < 32; ++k) mx = fmaxf(mx, lgS[k][t]);
        float sum = 0.0f;
#pragma unroll
        for (int k = 0; k < 32; ++k) sum += __expf(lgS[k][t] - mx);
        mxS[t] = mx;
        invS[t] = 1.0f / sum;
    }
    __syncthreads();
    {
        int k = t >> 3, h = t & 7;
        alS[k][h] = __expf(lgS[k][h] - mxS[h]) * invS[h];
    }
    __syncthreads();

    // ================= phase C: vw recompute + alpha aggregation (bf16 gather) ====
    {
        int c = t, h = c >> 5;
        float b3c = rv_b3[c];
        float w3r[16];
        const float4* w3p = (const float4*)(rv_w3 + c * 16);
#pragma unroll
        for (int i4 = 0; i4 < 4; ++i4) {
            float4 w = w3p[i4];
            w3r[i4 * 4 + 0] = w.x; w3r[i4 * 4 + 1] = w.y;
            w3r[i4 * 4 + 2] = w.z; w3r[i4 * 4 + 3] = w.w;
        }
        float acc[9];
#pragma unroll
        for (int m = 0; m < 9; ++m) acc[m] = 0.0f;
        for (int k = 0; k < 32; ++k) {
            float a = alS[k][h];
            float vw = b3c;
#pragma unroll
            for (int i = 0; i < 16; ++i) vw = fmaf(h2vS[k][i], w3r[i], vw);
            float av = a * vw;
            const unsigned short* crow = clh + (size_t)idxk[k] * 2304 + c;
#pragma unroll
            for (int m = 0; m < 9; ++m) acc[m] = fmaf(av, bfld_nt(crow + m * 256), acc[m]);
        }
#pragma unroll
        for (int m = 0; m < 9; ++m) outS[m][c] = acc[m];
    }
    __syncthreads();

    // ================= phase D: final so3_linear (wz, +bz on l=0) =================
    {
        float o[9];
        float bias = bz[t];
        o[0] = bias;
#pragma unroll
        for (int m = 1; m < 9; ++m) o[m] = 0.0f;
        const float4* wz0 = (const float4*)(wz + ((size_t)0 * 256 + t) * 256);
        const float4* wz1 = (const float4*)(wz + ((size_t)1 * 256 + t) * 256);
        const float4* wz2 = (const float4*)(wz + ((size_t)2 * 256 + t) * 256);
        for (int c4 = 0; c4 < 64; ++c4) {
            float4 w0 = wz0[c4], w1 = wz1[c4], w2 = wz2[c4];
            {
                float4 x = *(const float4*)&outS[0][c4 * 4];
                o[0] = fmaf(x.x, w0.x, fmaf(x.y, w0.y, fmaf(x.z, w0.z, fmaf(x.w, w0.w, o[0]))));
            }
#pragma unroll
            for (int m = 1; m < 4; ++m) {
                float4 x = *(const float4*)&outS[m][c4 * 4];
                o[m] = fmaf(x.x, w1.x, fmaf(x.y, w1.y, fmaf(x.z, w1.z, fmaf(x.w, w1.w, o[m]))));
            }
#pragma unroll
            for (int m = 4; m < 9; ++m) {
                float4 x = *(const float4*)&outS[m][c4 * 4];
                o[m] = fmaf(x.x, w2.x, fmaf(x.y, w2.y, fmaf(x.z, w2.z, fmaf(x.w, w2.w, o[m]))));
            }
        }
#pragma unroll
        for (int m = 0; m < 9; ++m) outfin[((size_t)n * 9 + m) * 256 + t] = o[m];
    }
}

// ---------------- launch ----------------
extern "C" void kernel_launch(void* const* d_in, const int* in_sizes, int n_in,
                              void* d_out, int out_size, void* d_ws, size_t ws_size,
                              hipStream_t stream)
{
    (void)in_sizes; (void)n_in; (void)out_size; (void)ws_size;

    const float* node_irreps = (const float*)d_in[1];
    const float* edge_vec    = (const float*)d_in[3];
    const float* attn_weight = (const float*)d_in[4];
    const int*   atom_num    = (const int*)d_in[5];
    const void*  attn_mask   = d_in[6];
    const int*   f_idx       = (const int*)d_in[7];
    const float* clus        = (const float*)d_in[8];
    const float* tgt_emb     = (const float*)d_in[9];
    const float* W_dot       = (const float*)d_in[10];
    const float* b_dot       = (const float*)d_in[11];
    const float* rm0_w1 = (const float*)d_in[12];
    const float* rm0_b1 = (const float*)d_in[13];
    const float* rm0_g1 = (const float*)d_in[14];
    const float* rm0_be1 = (const float*)d_in[15];
    const float* rm0_w2 = (const float*)d_in[16];
    const float* rm0_b2 = (const float*)d_in[17];
    const float* rm0_g2 = (const float*)d_in[18];
    const float* rm0_be2 = (const float*)d_in[19];
    const float* rm0_w3 = (const float*)d_in[20];
    const float* rm0_b3 = (const float*)d_in[21];
    const float* fcw = (const float*)d_in[22];
    const float* fcb = (const float*)d_in[23];
    const float* an_g = (const float*)d_in[24];
    const float* an_b = (const float*)d_in[25];
    const float* alpha_dot = (const float*)d_in[26];
    const float* rv_w1 = (const float*)d_in[27];
    const float* rv_b1 = (const float*)d_in[28];
    const float* rv_g1 = (const float*)d_in[29];
    const float* rv_be1 = (const float*)d_in[30];
    const float* rv_w2 = (const float*)d_in[31];
    const float* rv_b2 = (const float*)d_in[32];
    const float* rv_g2 = (const float*)d_in[33];
    const float* rv_be2 = (const float*)d_in[34];
    const float* rv_w3 = (const float*)d_in[35];
    const float* rv_b3 = (const float*)d_in[36];
    const float* wz = (const float*)d_in[37];
    const float* bz = (const float*)d_in[38];

    float* ws = (float*)d_ws;
    int* flag = (int*)d_ws;
    float* q_ws = ws + 16;                                   // 2048*288 fp32
    unsigned short* keyh = (unsigned short*)(q_ws + (size_t)NNODE * 288);   // 2048*288 bf16
    float* TA_ws = (float*)(keyh + (size_t)MCLUS * 288);     // 256*32
    float* CA_ws = TA_ws + 256 * 32;                         // 2048*32
    unsigned short* clh = (unsigned short*)(CA_ws + (size_t)MCLUS * 32);    // 2048*2304 bf16
    float* outfin = (float*)d_out;

    hipMemsetAsync(flag, 0, sizeof(int), stream);
    k0_detect<<<64, 256, 0, stream>>>((const unsigned int*)attn_mask, flag);
    kconv<<<MCLUS, 256, 0, stream>>>(clus, clh);
    kpre<<<288, 256, 0, stream>>>(tgt_emb, clus, rm0_w1, rv_w1, TA_ws, CA_ws);
    k1_so3qk<<<1152, 256, 0, stream>>>(node_irreps, clus, W_dot, b_dot, q_ws, keyh);
    k2_fused<<<NNODE, 256, 0, stream>>>(
        attn_weight, attn_mask, flag, f_idx, edge_vec, atom_num, clh,
        q_ws, keyh, TA_ws, CA_ws,
        rm0_w1, rm0_b1, rm0_g1, rm0_be1, rm0_w2, rm0_b2, rm0_g2, rm0_be2, rm0_w3, rm0_b3,
        fcw, fcb, an_g, an_b, alpha_dot,
        rv_w1, rv_b1, rv_g1, rv_be1, rv_w2, rv_b2, rv_g2, rv_be2, rv_w3, rv_b3,
        wz, bz, outfin);
}

// Round 5
// 668.544 us; speedup vs baseline: 1.5106x; 1.5106x over previous
//
#include <hip/hip_runtime.h>
#include <math.h>

#define NNODE 2048
#define MCLUS 2048
#define KNBR  32
#define CDIM  256
#define HHEAD 8

__device__ __forceinline__ float sigf(float x) { return 1.0f / (1.0f + __expf(-x)); }

__device__ __forceinline__ unsigned short f2bf(float f) {
    unsigned x = __float_as_uint(f);
    unsigned r = ((x >> 16) & 1u) + 0x7FFFu;
    return (unsigned short)((x + r) >> 16);
}
__device__ __forceinline__ float bf2f(unsigned short u) {
    return __uint_as_float(((unsigned)u) << 16);
}

// ---------------- K0: detect attn_mask storage layout ----------------
__global__ void k0_detect(const unsigned int* __restrict__ mw, int* __restrict__ flag) {
    int i = blockIdx.x * blockDim.x + threadIdx.x;
    unsigned int w = mw[i];
    int vb = (w != 0u && w != 1u && w != 0x3F800000u) ? 1 : 0;
    int vf = (w == 0x3F800000u) ? 1 : 0;
    unsigned long long bal_b = __ballot(vb);
    unsigned long long bal_f = __ballot(vf);
    if ((threadIdx.x & 63) == 0) {
        if (bal_b) atomicOr(flag, 1);
        if (bal_f) atomicOr(flag, 2);
    }
}

__device__ __forceinline__ bool edge_masked(const void* mp, int mode, int e) {
    if (mode & 2) return ((const float*)mp)[e] != 0.0f;
    if (mode & 1) return ((const unsigned char*)mp)[e] != 0;
    return ((const int*)mp)[e] != 0;
}

// ---------------- Kconv: clus fp32 -> bf16 copy ----------------
__global__ __launch_bounds__(256) void kconv(const float* __restrict__ clus,
                                             unsigned short* __restrict__ clh) {
    size_t base = (size_t)blockIdx.x * 2304;
    int t = threadIdx.x;
#pragma unroll
    for (int r = 0; r < 9; ++r) {
        int o = r * 256 + t;
        clh[base + o] = f2bf(clus[base + o]);
    }
}

// ---------------- Kpre: fold tgt/cl_scal parts of radial layer-1 ----------------
__global__ __launch_bounds__(256) void kpre(
    const float* __restrict__ tgt_emb, const float* __restrict__ clus,
    const float* __restrict__ rm0_w1, const float* __restrict__ rv_w1,
    float* __restrict__ TA, float* __restrict__ CA)
{
    int b = blockIdx.x, t = threadIdx.x;
    int slot = t & 31, j = slot & 15, mlp = slot >> 4;
    const float* w1 = mlp ? rv_w1 : rm0_w1;
    if (b < 32) {
        int a = b * 8 + (t >> 5);
        const float* x = tgt_emb + (size_t)a * 128;
        const float* w = w1 + j * 416 + 32;
        float acc = 0.0f;
        for (int i = 0; i < 128; i += 4)
            acc = fmaf(x[i], w[i], fmaf(x[i+1], w[i+1], fmaf(x[i+2], w[i+2], fmaf(x[i+3], w[i+3], acc))));
        TA[a * 32 + slot] = acc;
    } else {
        int m = (b - 32) * 8 + (t >> 5);
        const float* x = clus + (size_t)m * 2304;
        const float* w = w1 + j * 416 + 160;
        float acc = 0.0f;
        for (int i = 0; i < 256; i += 4)
            acc = fmaf(x[i], w[i], fmaf(x[i+1], w[i+1], fmaf(x[i+2], w[i+2], fmaf(x[i+3], w[i+3], acc))));
        CA[m * 32 + slot] = acc;
    }
}

// ---------------- K1: so3_linear; q (fp32) for nodes, key (bf16) for clusters ----
__global__ __launch_bounds__(256) void k1_so3qk(
    const float* __restrict__ nodei, const float* __restrict__ clus,
    const float* __restrict__ W_dot, const float* __restrict__ b_dot,
    float* __restrict__ q_ws, unsigned short* __restrict__ keyh)
{
    __shared__ __align__(16) float X[32][256];
    __shared__ int rx[32], rmm[32];
    int b = blockIdx.x, t = threadIdx.x;
    int l, vr0, nm, moff;
    if (b < 128)      { l = 0; vr0 = b * 32;         nm = 1; moff = 0; }
    else if (b < 512) { l = 1; vr0 = (b - 128) * 32; nm = 3; moff = 1; }
    else              { l = 2; vr0 = (b - 512) * 32; nm = 5; moff = 4; }
    if (t < 32) {
        int vr = vr0 + t;
        rx[t] = vr / nm;
        rmm[t] = moff + vr % nm;
    }
    __syncthreads();
    for (int e = t; e < 32 * 256; e += 256) {
        int r = e >> 8, c = e & 255;
        int x = rx[r], m = rmm[r];
        const float* src = (x < NNODE) ? (nodei + ((size_t)x * 9 + m) * 256)
                                       : (clus + ((size_t)(x - NNODE) * 9 + m) * 256);
        X[r][c] = src[c];
    }
    __syncthreads();
    int d = t & 31, rg = t >> 5;
    int r0 = rg * 4;
    const float4* wrow = (const float4*)(W_dot + ((size_t)l * 32 + d) * 256);
    float acc[4];
    float bd = (l == 0) ? b_dot[d] : 0.0f;
#pragma unroll
    for (int jj = 0; jj < 4; ++jj) acc[jj] = bd;
    for (int c4 = 0; c4 < 64; ++c4) {
        float4 w = wrow[c4];
#pragma unroll
        for (int jj = 0; jj < 4; ++jj) {
            float4 x4 = *(const float4*)&X[r0 + jj][c4 * 4];
            acc[jj] = fmaf(x4.x, w.x, fmaf(x4.y, w.y, fmaf(x4.z, w.z, fmaf(x4.w, w.w, acc[jj]))));
        }
    }
#pragma unroll
    for (int jj = 0; jj < 4; ++jj) {
        int r = r0 + jj;
        int x = rx[r], m = rmm[r];
        if (x < NNODE) q_ws[((size_t)x * 9 + m) * 32 + d] = acc[jj];
        else           keyh[((size_t)(x - NNODE) * 9 + m) * 32 + d] = f2bf(acc[jj]);
    }
}

// ---------------- K2: fused per-node pipeline ----------------
__device__ __forceinline__ float lnsilu16(float x, float g, float b) {
    float s = x;
#pragma unroll
    for (int m = 1; m < 16; m <<= 1) s += __shfl_xor(s, m, 16);
    float mu = s * 0.0625f;
    float d = x - mu;
    float s2 = d * d;
#pragma unroll
    for (int m = 1; m < 16; m <<= 1) s2 += __shfl_xor(s2, m, 16);
    float y = d * rsqrtf(s2 * 0.0625f + 1e-5f) * g + b;
    return y * sigf(y);
}

__global__ __launch_bounds__(256, 2) void k2_fused(
    const float* __restrict__ attn_weight, const void* __restrict__ mask,
    const int* __restrict__ mflag,
    const int* __restrict__ f_idx, const float* __restrict__ edge_vec,
    const int* __restrict__ atom_num, const unsigned short* __restrict__ clh,
    const float* __restrict__ q_ws, const unsigned short* __restrict__ keyh,
    const float* __restrict__ TA, const float* __restrict__ CA,
    const float* __restrict__ rm0_w1, const float* __restrict__ rm0_b1,
    const float* __restrict__ rm0_g1, const float* __restrict__ rm0_be1,
    const float* __restrict__ rm0_w2, const float* __restrict__ rm0_b2,
    const float* __restrict__ rm0_g2, const float* __restrict__ rm0_be2,
    const float* __restrict__ rm0_w3, const float* __restrict__ rm0_b3,
    const float* __restrict__ fcw, const float* __restrict__ fcb,
    const float* __restrict__ an_g, const float* __restrict__ an_b,
    const float* __restrict__ alpha_dot,
    const float* __restrict__ rv_w1, const float* __restrict__ rv_b1,
    const float* __restrict__ rv_g1, const float* __restrict__ rv_be1,
    const float* __restrict__ rv_w2, const float* __restrict__ rv_b2,
    const float* __restrict__ rv_g2, const float* __restrict__ rv_be2,
    const float* __restrict__ rv_w3, const float* __restrict__ rv_b3,
    float* __restrict__ outpre)
{
    __shared__ float qn[288];
    __shared__ float Ts[32];
    __shared__ float shS[32][9];
    __shared__ float awS[32][32];
    __shared__ float caS[32][32];
    __shared__ __align__(16) float mwaS[32][196];
    __shared__ float h2vS[32][17];
    __shared__ float lgS[32][8];
    __shared__ float alS[32][8];
    __shared__ float mxS[8], invS[8];
    __shared__ int idxk[32], maskk[32];

    int n = blockIdx.x, t = threadIdx.x;
    int mode = mflag[0];

    for (int i = t; i < 288; i += 256) qn[i] = q_ws[(size_t)n * 288 + i];
    if (t < 32) {
        int an = atom_num[n];
        Ts[t] = TA[an * 32 + t];
        int e = n * KNBR + t;
        idxk[t] = f_idx[e];
        maskk[t] = edge_masked(mask, mode, e) ? 1 : 0;
        float vx = edge_vec[(size_t)e * 3 + 0];
        float vy = edge_vec[(size_t)e * 3 + 1];
        float vz = edge_vec[(size_t)e * 3 + 2];
        float inv = 1.0f / (sqrtf(vx * vx + vy * vy + vz * vz) + 1e-12f);
        float x = vx * inv, y = vy * inv, z = vz * inv;
        shS[t][0] = 0.28209479177387814f;
        shS[t][1] = 0.4886025119029199f * y;
        shS[t][2] = 0.4886025119029199f * z;
        shS[t][3] = 0.4886025119029199f * x;
        shS[t][4] = 1.0925484305920792f * x * y;
        shS[t][5] = 1.0925484305920792f * y * z;
        shS[t][6] = 0.31539156525252005f * (3.0f * z * z - 1.0f);
        shS[t][7] = 1.0925484305920792f * x * z;
        shS[t][8] = 0.5462742152960396f * (x * x - y * y);
    }
    __syncthreads();
    for (int e2 = t; e2 < 1024; e2 += 256) {
        int ek = e2 >> 5, i = e2 & 31;
        awS[ek][i] = maskk[ek] ? 0.0f : attn_weight[((size_t)(n * KNBR + ek)) * 32 + i];
        caS[ek][i] = CA[(size_t)idxk[ek] * 32 + i];
    }
    __syncthreads();

    // ================= phase A: edge MLPs (wave-parallel, 16-lane groups) =========
    {
        int g = t >> 4, j = t & 15;
        for (int ee = 0; ee < 2; ++ee) {
            int e = g + ee * 16;
            int idx = idxk[e];
            float accm = rm0_b1[j] + Ts[j] + caS[e][j];
            float accv = rv_b1[j] + Ts[16 + j] + caS[e][16 + j];
            const float* w1m = rm0_w1 + j * 416;
            const float* w1v = rv_w1 + j * 416;
#pragma unroll
            for (int i = 0; i < 32; i += 4) {
                float a0 = awS[e][i], a1 = awS[e][i + 1], a2 = awS[e][i + 2], a3 = awS[e][i + 3];
                accm = fmaf(a0, w1m[i], fmaf(a1, w1m[i+1], fmaf(a2, w1m[i+2], fmaf(a3, w1m[i+3], accm))));
                accv = fmaf(a0, w1v[i], fmaf(a1, w1v[i+1], fmaf(a2, w1v[i+2], fmaf(a3, w1v[i+3], accv))));
            }
            float hm = lnsilu16(accm, rm0_g1[j], rm0_be1[j]);
            float hv = lnsilu16(accv, rv_g1[j], rv_be1[j]);
            float am2 = rm0_b2[j], av2 = rv_b2[j];
#pragma unroll
            for (int i = 0; i < 16; ++i) {
                am2 = fmaf(__shfl(hm, i, 16), rm0_w2[j * 16 + i], am2);
                av2 = fmaf(__shfl(hv, i, 16), rv_w2[j * 16 + i], av2);
            }
            float h2m = lnsilu16(am2, rm0_g2[j], rm0_be2[j]);
            float h2v = lnsilu16(av2, rv_g2[j], rv_be2[j]);
            h2vS[e][j] = h2v;

            const unsigned short* keyrow = keyh + (size_t)idx * 288;
            float h16[16];
#pragma unroll
            for (int i = 0; i < 16; ++i) h16[i] = __shfl(h2m, i, 16);
#pragma unroll
            for (int r = 0; r < 12; ++r) {
                int d = r * 16 + j;
                const float* w3 = rm0_w3 + d * 16;
                float ew = rm0_b3[d];
#pragma unroll
                for (int i = 0; i < 16; ++i) ew = fmaf(h16[i], w3[i], ew);
                int c = ((r & 1) << 4) + j;   // d & 31
                int bb = r >> 1;              // d >> 5
                float m0v;
                if (bb == 0)      m0v = qn[c] * shS[e][0];
                else if (bb == 1) m0v = qn[32 + c] * shS[e][1] + qn[64 + c] * shS[e][2]
                                      + qn[96 + c] * shS[e][3];
                else if (bb == 2) m0v = qn[128 + c] * shS[e][4] + qn[160 + c] * shS[e][5]
                                      + qn[192 + c] * shS[e][6] + qn[224 + c] * shS[e][7]
                                      + qn[256 + c] * shS[e][8];
                else if (bb == 3) m0v = bf2f(keyrow[c]) * shS[e][0];
                else if (bb == 4) m0v = bf2f(keyrow[32 + c]) * shS[e][1]
                                      + bf2f(keyrow[64 + c]) * shS[e][2]
                                      + bf2f(keyrow[96 + c]) * shS[e][3];
                else              m0v = bf2f(keyrow[128 + c]) * shS[e][4]
                                      + bf2f(keyrow[160 + c]) * shS[e][5]
                                      + bf2f(keyrow[192 + c]) * shS[e][6]
                                      + bf2f(keyrow[224 + c]) * shS[e][7]
                                      + bf2f(keyrow[256 + c]) * shS[e][8];
                mwaS[e][d] = ew * m0v;
            }
        }
    }
    __syncthreads();

    // ================= phase B: af GEMM + LN + smooth_leaky + logits ==============
    {
        int h = t >> 5, s = t & 31;
        float ang = an_g[s], anb = an_b[s], ad = alpha_dot[h * 32 + s];
        float bias = fcb[t];
        const float4* fr = (const float4*)(fcw + (size_t)t * 192);
#pragma unroll
        for (int chunk = 0; chunk < 2; ++chunk) {
            float acc[16];
#pragma unroll
            for (int e = 0; e < 16; ++e) acc[e] = bias;
            for (int i4 = 0; i4 < 48; ++i4) {
                float4 wv = fr[i4];
#pragma unroll
                for (int e = 0; e < 16; ++e) {
                    float4 m4 = *(const float4*)&mwaS[chunk * 16 + e][i4 * 4];
                    acc[e] = fmaf(m4.x, wv.x, fmaf(m4.y, wv.y, fmaf(m4.z, wv.z, fmaf(m4.w, wv.w, acc[e]))));
                }
            }
#pragma unroll
            for (int ee = 0; ee < 16; ++ee) {
                int e = chunk * 16 + ee;
                float v = acc[ee];
                float su = v;
#pragma unroll
                for (int m = 1; m < 32; m <<= 1) su += __shfl_xor(su, m, 32);
                float mu = su * (1.0f / 32.0f);
                float dd = v - mu;
                float s2 = dd * dd;
#pragma unroll
                for (int m = 1; m < 32; m <<= 1) s2 += __shfl_xor(s2, m, 32);
                float rs = rsqrtf(s2 * (1.0f / 32.0f) + 1e-5f);
                float y = dd * rs * ang + anb;
                float sl = 0.6f * y + 0.4f * y * (2.0f * sigf(y) - 1.0f);
                float lgv = sl * ad;
#pragma unroll
                for (int m = 1; m < 32; m <<= 1) lgv += __shfl_xor(lgv, m, 32);
                if (s == 0) lgS[e][h] = maskk[e] ? -1e9f : lgv;
            }
        }
    }
    __syncthreads();

    // ================= softmax over k ============================================
    if (t < 8) {
        float mx = -1e30f;
#pragma unroll
        for (int k = 0; k < 32; ++k) mx = fmaxf(mx, lgS[k][t]);
        float sum = 0.0f;
#pragma unroll
        for (int k = 0; k < 32; ++k) sum += __expf(lgS[k][t] - mx);
        mxS[t] = mx;
        invS[t] = 1.0f / sum;
    }
    __syncthreads();
    {
        int k = t >> 3, h = t & 7;
        alS[k][h] = __expf(lgS[k][h] - mxS[h]) * invS[h];
    }
    __syncthreads();

    // ================= phase C: vw recompute + alpha aggregation (bf16 gather) ====
    {
        int c = t, h = c >> 5;
        float b3c = rv_b3[c];
        float w3r[16];
        const float4* w3p = (const float4*)(rv_w3 + c * 16);
#pragma unroll
        for (int i4 = 0; i4 < 4; ++i4) {
            float4 w = w3p[i4];
            w3r[i4 * 4 + 0] = w.x; w3r[i4 * 4 + 1] = w.y;
            w3r[i4 * 4 + 2] = w.z; w3r[i4 * 4 + 3] = w.w;
        }
        float acc[9];
#pragma unroll
        for (int m = 0; m < 9; ++m) acc[m] = 0.0f;
        for (int k = 0; k < 32; ++k) {
            float a = alS[k][h];
            float vw = b3c;
#pragma unroll
            for (int i = 0; i < 16; ++i) vw = fmaf(h2vS[k][i], w3r[i], vw);
            float av = a * vw;
            const unsigned short* crow = clh + (size_t)idxk[k] * 2304 + c;
#pragma unroll
            for (int m = 0; m < 9; ++m) acc[m] = fmaf(av, bf2f(crow[m * 256]), acc[m]);
        }
#pragma unroll
        for (int m = 0; m < 9; ++m) outpre[((size_t)n * 9 + m) * 256 + c] = acc[m];
    }
}

// ---------------- K5: final so3_linear with wz (+bz on l=0), in-place on d_out ----
__global__ __launch_bounds__(256) void k5_final(
    const float* __restrict__ wz, const float* __restrict__ bz,
    float* __restrict__ io)
{
    __shared__ __align__(16) float X[32][256];
    __shared__ int rr[32];
    int b = blockIdx.x, t = threadIdx.x;
    int l, vr0, nm, moff;
    if (b < 64)       { l = 0; vr0 = b * 32;         nm = 1; moff = 0; }
    else if (b < 256) { l = 1; vr0 = (b - 64) * 32;  nm = 3; moff = 1; }
    else              { l = 2; vr0 = (b - 256) * 32; nm = 5; moff = 4; }
    if (t < 32) {
        int vr = vr0 + t;
        int n = vr / nm, m = moff + vr % nm;
        rr[t] = n * 9 + m;
    }
    __syncthreads();
    for (int e = t; e < 32 * 256; e += 256) {
        int r = e >> 8, c = e & 255;
        X[r][c] = io[(size_t)rr[r] * 256 + c];
    }
    __syncthreads();
    int d = t;
    float acc[32];
    float bias = (l == 0) ? bz[d] : 0.0f;
#pragma unroll
    for (int r = 0; r < 32; ++r) acc[r] = bias;
    const float4* w = (const float4*)(wz + ((size_t)l * 256 + d) * 256);
    for (int c4 = 0; c4 < 64; ++c4) {
        float4 wv = w[c4];
#pragma unroll
        for (int r = 0; r < 32; ++r) {
            float4 x4 = *(const float4*)&X[r][c4 * 4];
            acc[r] = fmaf(x4.x, wv.x, fmaf(x4.y, wv.y, fmaf(x4.z, wv.z, fmaf(x4.w, wv.w, acc[r]))));
        }
    }
#pragma unroll
    for (int r = 0; r < 32; ++r) io[(size_t)rr[r] * 256 + d] = acc[r];
}

// ---------------- launch ----------------
extern "C" void kernel_launch(void* const* d_in, const int* in_sizes, int n_in,
                              void* d_out, int out_size, void* d_ws, size_t ws_size,
                              hipStream_t stream)
{
    (void)in_sizes; (void)n_in; (void)out_size; (void)ws_size;

    const float* node_irreps = (const float*)d_in[1];
    const float* edge_vec    = (const float*)d_in[3];
    const float* attn_weight = (const float*)d_in[4];
    const int*   atom_num    = (const int*)d_in[5];
    const void*  attn_mask   = d_in[6];
    const int*   f_idx       = (const int*)d_in[7];
    const float* clus        = (const float*)d_in[8];
    const float* tgt_emb     = (const float*)d_in[9];
    const float* W_dot       = (const float*)d_in[10];
    const float* b_dot       = (const float*)d_in[11];
    const float* rm0_w1 = (const float*)d_in[12];
    const float* rm0_b1 = (const float*)d_in[13];
    const float* rm0_g1 = (const float*)d_in[14];
    const float* rm0_be1 = (const float*)d_in[15];
    const float* rm0_w2 = (const float*)d_in[16];
    const float* rm0_b2 = (const float*)d_in[17];
    const float* rm0_g2 = (const float*)d_in[18];
    const float* rm0_be2 = (const float*)d_in[19];
    const float* rm0_w3 = (const float*)d_in[20];
    const float* rm0_b3 = (const float*)d_in[21];
    const float* fcw = (const float*)d_in[22];
    const float* fcb = (const float*)d_in[23];
    const float* an_g = (const float*)d_in[24];
    const float* an_b = (const float*)d_in[25];
    const float* alpha_dot = (const float*)d_in[26];
    const float* rv_w1 = (const float*)d_in[27];
    const float* rv_b1 = (const float*)d_in[28];
    const float* rv_g1 = (const float*)d_in[29];
    const float* rv_be1 = (const float*)d_in[30];
    const float* rv_w2 = (const float*)d_in[31];
    const float* rv_b2 = (const float*)d_in[32];
    const float* rv_g2 = (const float*)d_in[33];
    const float* rv_be2 = (const float*)d_in[34];
    const float* rv_w3 = (const float*)d_in[35];
    const float* rv_b3 = (const float*)d_in[36];
    const float* wz = (const float*)d_in[37];
    const float* bz = (const float*)d_in[38];

    float* ws = (float*)d_ws;
    int* flag = (int*)d_ws;
    float* q_ws = ws + 16;                                   // 2048*288 fp32
    unsigned short* keyh = (unsigned short*)(q_ws + (size_t)NNODE * 288);   // 2048*288 bf16
    float* TA_ws = (float*)(keyh + (size_t)MCLUS * 288);     // 256*32
    float* CA_ws = TA_ws + 256 * 32;                         // 2048*32
    unsigned short* clh = (unsigned short*)(CA_ws + (size_t)MCLUS * 32);    // 2048*2304 bf16
    float* outpre = (float*)d_out;

    hipMemsetAsync(flag, 0, sizeof(int), stream);
    k0_detect<<<64, 256, 0, stream>>>((const unsigned int*)attn_mask, flag);
    kconv<<<MCLUS, 256, 0, stream>>>(clus, clh);
    kpre<<<288, 256, 0, stream>>>(tgt_emb, clus, rm0_w1, rv_w1, TA_ws, CA_ws);
    k1_so3qk<<<1152, 256, 0, stream>>>(node_irreps, clus, W_dot, b_dot, q_ws, keyh);
    k2_fused<<<NNODE, 256, 0, stream>>>(
        attn_weight, attn_mask, flag, f_idx, edge_vec, atom_num, clh,
        q_ws, keyh, TA_ws, CA_ws,
        rm0_w1, rm0_b1, rm0_g1, rm0_be1, rm0_w2, rm0_b2, rm0_g2, rm0_be2, rm0_w3, rm0_b3,
        fcw, fcb, an_g, an_b, alpha_dot,
        rv_w1, rv_b1, rv_g1, rv_be1, rv_w2, rv_b2, rv_g2, rv_be2, rv_w3, rv_b3,
        outpre);
    k5_final<<<576, 256, 0, stream>>>(wz, bz, outpre);
}

// Round 6
// 655.457 us; speedup vs baseline: 1.5408x; 1.0200x over previous
//
#include <hip/hip_runtime.h>
#include <math.h>

#define NNODE 2048
#define MCLUS 2048
#define KNBR  32
#define CDIM  256
#define HHEAD 8

__device__ __forceinline__ float sigf(float x) { return 1.0f / (1.0f + __expf(-x)); }

__device__ __forceinline__ unsigned short f2bf(float f) {
    unsigned x = __float_as_uint(f);
    unsigned r = ((x >> 16) & 1u) + 0x7FFFu;
    return (unsigned short)((x + r) >> 16);
}
__device__ __forceinline__ float bf2f(unsigned short u) {
    return __uint_as_float(((unsigned)u) << 16);
}

// ---------------- K0: detect attn_mask storage layout ----------------
__global__ void k0_detect(const unsigned int* __restrict__ mw, int* __restrict__ flag) {
    int i = blockIdx.x * blockDim.x + threadIdx.x;
    unsigned int w = mw[i];
    int vb = (w != 0u && w != 1u && w != 0x3F800000u) ? 1 : 0;
    int vf = (w == 0x3F800000u) ? 1 : 0;
    unsigned long long bal_b = __ballot(vb);
    unsigned long long bal_f = __ballot(vf);
    if ((threadIdx.x & 63) == 0) {
        if (bal_b) atomicOr(flag, 1);
        if (bal_f) atomicOr(flag, 2);
    }
}

__device__ __forceinline__ bool edge_masked(const void* mp, int mode, int e) {
    if (mode & 2) return ((const float*)mp)[e] != 0.0f;
    if (mode & 1) return ((const unsigned char*)mp)[e] != 0;
    return ((const int*)mp)[e] != 0;
}

// ---------------- Kconv: clus fp32 -> bf16 copy ----------------
__global__ __launch_bounds__(256) void kconv(const float* __restrict__ clus,
                                             unsigned short* __restrict__ clh) {
    size_t base = (size_t)blockIdx.x * 2304;
    int t = threadIdx.x;
#pragma unroll
    for (int r = 0; r < 9; ++r) {
        int o = r * 256 + t;
        clh[base + o] = f2bf(clus[base + o]);
    }
}

// ---------------- Kpre: fold tgt/cl_scal parts of radial layer-1 ----------------
__global__ __launch_bounds__(256) void kpre(
    const float* __restrict__ tgt_emb, const float* __restrict__ clus,
    const float* __restrict__ rm0_w1, const float* __restrict__ rv_w1,
    float* __restrict__ TA, float* __restrict__ CA)
{
    int b = blockIdx.x, t = threadIdx.x;
    int slot = t & 31, j = slot & 15, mlp = slot >> 4;
    const float* w1 = mlp ? rv_w1 : rm0_w1;
    if (b < 32) {
        int a = b * 8 + (t >> 5);
        const float* x = tgt_emb + (size_t)a * 128;
        const float* w = w1 + j * 416 + 32;
        float acc = 0.0f;
        for (int i = 0; i < 128; i += 4)
            acc = fmaf(x[i], w[i], fmaf(x[i+1], w[i+1], fmaf(x[i+2], w[i+2], fmaf(x[i+3], w[i+3], acc))));
        TA[a * 32 + slot] = acc;
    } else {
        int m = (b - 32) * 8 + (t >> 5);
        const float* x = clus + (size_t)m * 2304;
        const float* w = w1 + j * 416 + 160;
        float acc = 0.0f;
        for (int i = 0; i < 256; i += 4)
            acc = fmaf(x[i], w[i], fmaf(x[i+1], w[i+1], fmaf(x[i+2], w[i+2], fmaf(x[i+3], w[i+3], acc))));
        CA[m * 32 + slot] = acc;
    }
}

// ---------------- K1: so3_linear; q (fp32) for nodes, key (bf16) for clusters ----
__global__ __launch_bounds__(256) void k1_so3qk(
    const float* __restrict__ nodei, const float* __restrict__ clus,
    const float* __restrict__ W_dot, const float* __restrict__ b_dot,
    float* __restrict__ q_ws, unsigned short* __restrict__ keyh)
{
    __shared__ __align__(16) float X[32][256];
    __shared__ int rx[32], rmm[32];
    int b = blockIdx.x, t = threadIdx.x;
    int l, vr0, nm, moff;
    if (b < 128)      { l = 0; vr0 = b * 32;         nm = 1; moff = 0; }
    else if (b < 512) { l = 1; vr0 = (b - 128) * 32; nm = 3; moff = 1; }
    else              { l = 2; vr0 = (b - 512) * 32; nm = 5; moff = 4; }
    if (t < 32) {
        int vr = vr0 + t;
        rx[t] = vr / nm;
        rmm[t] = moff + vr % nm;
    }
    __syncthreads();
    for (int e = t; e < 32 * 256; e += 256) {
        int r = e >> 8, c = e & 255;
        int x = rx[r], m = rmm[r];
        const float* src = (x < NNODE) ? (nodei + ((size_t)x * 9 + m) * 256)
                                       : (clus + ((size_t)(x - NNODE) * 9 + m) * 256);
        X[r][c] = src[c];
    }
    __syncthreads();
    int d = t & 31, rg = t >> 5;
    int r0 = rg * 4;
    const float4* wrow = (const float4*)(W_dot + ((size_t)l * 32 + d) * 256);
    float acc[4];
    float bd = (l == 0) ? b_dot[d] : 0.0f;
#pragma unroll
    for (int jj = 0; jj < 4; ++jj) acc[jj] = bd;
    for (int c4 = 0; c4 < 64; ++c4) {
        float4 w = wrow[c4];
#pragma unroll
        for (int jj = 0; jj < 4; ++jj) {
            float4 x4 = *(const float4*)&X[r0 + jj][c4 * 4];
            acc[jj] = fmaf(x4.x, w.x, fmaf(x4.y, w.y, fmaf(x4.z, w.z, fmaf(x4.w, w.w, acc[jj]))));
        }
    }
#pragma unroll
    for (int jj = 0; jj < 4; ++jj) {
        int r = r0 + jj;
        int x = rx[r], m = rmm[r];
        if (x < NNODE) q_ws[((size_t)x * 9 + m) * 32 + d] = acc[jj];
        else           keyh[((size_t)(x - NNODE) * 9 + m) * 32 + d] = f2bf(acc[jj]);
    }
}

// ---------------- K2ab: edge MLPs + logits + softmax (compute-bound) -------------
__device__ __forceinline__ float lnsilu16(float x, float g, float b) {
    float s = x;
#pragma unroll
    for (int m = 1; m < 16; m <<= 1) s += __shfl_xor(s, m, 16);
    float mu = s * 0.0625f;
    float d = x - mu;
    float s2 = d * d;
#pragma unroll
    for (int m = 1; m < 16; m <<= 1) s2 += __shfl_xor(s2, m, 16);
    float y = d * rsqrtf(s2 * 0.0625f + 1e-5f) * g + b;
    return y * sigf(y);
}

__global__ __launch_bounds__(256) void k2ab(
    const float* __restrict__ attn_weight, const void* __restrict__ mask,
    const int* __restrict__ mflag,
    const int* __restrict__ f_idx, const float* __restrict__ edge_vec,
    const int* __restrict__ atom_num,
    const float* __restrict__ q_ws, const unsigned short* __restrict__ keyh,
    const float* __restrict__ TA, const float* __restrict__ CA,
    const float* __restrict__ rm0_w1, const float* __restrict__ rm0_b1,
    const float* __restrict__ rm0_g1, const float* __restrict__ rm0_be1,
    const float* __restrict__ rm0_w2, const float* __restrict__ rm0_b2,
    const float* __restrict__ rm0_g2, const float* __restrict__ rm0_be2,
    const float* __restrict__ rm0_w3, const float* __restrict__ rm0_b3,
    const float* __restrict__ fcw, const float* __restrict__ fcb,
    const float* __restrict__ an_g, const float* __restrict__ an_b,
    const float* __restrict__ alpha_dot,
    const float* __restrict__ rv_w1, const float* __restrict__ rv_b1,
    const float* __restrict__ rv_g1, const float* __restrict__ rv_be1,
    const float* __restrict__ rv_w2, const float* __restrict__ rv_b2,
    const float* __restrict__ rv_g2, const float* __restrict__ rv_be2,
    float* __restrict__ al_g, float* __restrict__ h2v_g)
{
    __shared__ float qn[288];
    __shared__ float Ts[32];
    __shared__ float shS[32][9];
    __shared__ float awS[32][32];
    __shared__ float caS[32][32];
    __shared__ __align__(16) float mwaS[32][196];
    __shared__ float lgS[32][8];
    __shared__ float mxS[8], invS[8];
    __shared__ int idxk[32], maskk[32];

    int n = blockIdx.x, t = threadIdx.x;
    int mode = mflag[0];

    for (int i = t; i < 288; i += 256) qn[i] = q_ws[(size_t)n * 288 + i];
    if (t < 32) {
        int an = atom_num[n];
        Ts[t] = TA[an * 32 + t];
        int e = n * KNBR + t;
        idxk[t] = f_idx[e];
        maskk[t] = edge_masked(mask, mode, e) ? 1 : 0;
        float vx = edge_vec[(size_t)e * 3 + 0];
        float vy = edge_vec[(size_t)e * 3 + 1];
        float vz = edge_vec[(size_t)e * 3 + 2];
        float inv = 1.0f / (sqrtf(vx * vx + vy * vy + vz * vz) + 1e-12f);
        float x = vx * inv, y = vy * inv, z = vz * inv;
        shS[t][0] = 0.28209479177387814f;
        shS[t][1] = 0.4886025119029199f * y;
        shS[t][2] = 0.4886025119029199f * z;
        shS[t][3] = 0.4886025119029199f * x;
        shS[t][4] = 1.0925484305920792f * x * y;
        shS[t][5] = 1.0925484305920792f * y * z;
        shS[t][6] = 0.31539156525252005f * (3.0f * z * z - 1.0f);
        shS[t][7] = 1.0925484305920792f * x * z;
        shS[t][8] = 0.5462742152960396f * (x * x - y * y);
    }
    __syncthreads();
    for (int e2 = t; e2 < 1024; e2 += 256) {
        int ek = e2 >> 5, i = e2 & 31;
        awS[ek][i] = maskk[ek] ? 0.0f : attn_weight[((size_t)(n * KNBR + ek)) * 32 + i];
        caS[ek][i] = CA[(size_t)idxk[ek] * 32 + i];
    }
    __syncthreads();

    // ===== phase A: edge MLPs (wave-parallel, 16-lane groups) =====
    {
        int g = t >> 4, j = t & 15;
        for (int ee = 0; ee < 2; ++ee) {
            int e = g + ee * 16;
            int idx = idxk[e];
            float accm = rm0_b1[j] + Ts[j] + caS[e][j];
            float accv = rv_b1[j] + Ts[16 + j] + caS[e][16 + j];
            const float* w1m = rm0_w1 + j * 416;
            const float* w1v = rv_w1 + j * 416;
#pragma unroll
            for (int i = 0; i < 32; i += 4) {
                float a0 = awS[e][i], a1 = awS[e][i + 1], a2 = awS[e][i + 2], a3 = awS[e][i + 3];
                accm = fmaf(a0, w1m[i], fmaf(a1, w1m[i+1], fmaf(a2, w1m[i+2], fmaf(a3, w1m[i+3], accm))));
                accv = fmaf(a0, w1v[i], fmaf(a1, w1v[i+1], fmaf(a2, w1v[i+2], fmaf(a3, w1v[i+3], accv))));
            }
            float hm = lnsilu16(accm, rm0_g1[j], rm0_be1[j]);
            float hv = lnsilu16(accv, rv_g1[j], rv_be1[j]);
            float am2 = rm0_b2[j], av2 = rv_b2[j];
#pragma unroll
            for (int i = 0; i < 16; ++i) {
                am2 = fmaf(__shfl(hm, i, 16), rm0_w2[j * 16 + i], am2);
                av2 = fmaf(__shfl(hv, i, 16), rv_w2[j * 16 + i], av2);
            }
            float h2m = lnsilu16(am2, rm0_g2[j], rm0_be2[j]);
            float h2v = lnsilu16(av2, rv_g2[j], rv_be2[j]);
            h2v_g[(size_t)n * 512 + e * 16 + j] = h2v;

            const unsigned short* keyrow = keyh + (size_t)idx * 288;
            float h16[16];
#pragma unroll
            for (int i = 0; i < 16; ++i) h16[i] = __shfl(h2m, i, 16);
#pragma unroll
            for (int r = 0; r < 12; ++r) {
                int d = r * 16 + j;
                const float* w3 = rm0_w3 + d * 16;
                float ew = rm0_b3[d];
#pragma unroll
                for (int i = 0; i < 16; ++i) ew = fmaf(h16[i], w3[i], ew);
                int c = ((r & 1) << 4) + j;   // d & 31
                int bb = r >> 1;              // d >> 5
                float m0v;
                if (bb == 0)      m0v = qn[c] * shS[e][0];
                else if (bb == 1) m0v = qn[32 + c] * shS[e][1] + qn[64 + c] * shS[e][2]
                                      + qn[96 + c] * shS[e][3];
                else if (bb == 2) m0v = qn[128 + c] * shS[e][4] + qn[160 + c] * shS[e][5]
                                      + qn[192 + c] * shS[e][6] + qn[224 + c] * shS[e][7]
                                      + qn[256 + c] * shS[e][8];
                else if (bb == 3) m0v = bf2f(keyrow[c]) * shS[e][0];
                else if (bb == 4) m0v = bf2f(keyrow[32 + c]) * shS[e][1]
                                      + bf2f(keyrow[64 + c]) * shS[e][2]
                                      + bf2f(keyrow[96 + c]) * shS[e][3];
                else              m0v = bf2f(keyrow[128 + c]) * shS[e][4]
                                      + bf2f(keyrow[160 + c]) * shS[e][5]
                                      + bf2f(keyrow[192 + c]) * shS[e][6]
                                      + bf2f(keyrow[224 + c]) * shS[e][7]
                                      + bf2f(keyrow[256 + c]) * shS[e][8];
                mwaS[e][d] = ew * m0v;
            }
        }
    }
    __syncthreads();

    // ===== phase B: af GEMM + LN + smooth_leaky + logits =====
    {
        int h = t >> 5, s = t & 31;
        float ang = an_g[s], anb = an_b[s], ad = alpha_dot[h * 32 + s];
        float bias = fcb[t];
        const float4* fr = (const float4*)(fcw + (size_t)t * 192);
#pragma unroll
        for (int chunk = 0; chunk < 2; ++chunk) {
            float acc[16];
#pragma unroll
            for (int e = 0; e < 16; ++e) acc[e] = bias;
            for (int i4 = 0; i4 < 48; ++i4) {
                float4 wv = fr[i4];
#pragma unroll
                for (int e = 0; e < 16; ++e) {
                    float4 m4 = *(const float4*)&mwaS[chunk * 16 + e][i4 * 4];
                    acc[e] = fmaf(m4.x, wv.x, fmaf(m4.y, wv.y, fmaf(m4.z, wv.z, fmaf(m4.w, wv.w, acc[e]))));
                }
            }
#pragma unroll
            for (int ee = 0; ee < 16; ++ee) {
                int e = chunk * 16 + ee;
                float v = acc[ee];
                float su = v;
#pragma unroll
                for (int m = 1; m < 32; m <<= 1) su += __shfl_xor(su, m, 32);
                float mu = su * (1.0f / 32.0f);
                float dd = v - mu;
                float s2 = dd * dd;
#pragma unroll
                for (int m = 1; m < 32; m <<= 1) s2 += __shfl_xor(s2, m, 32);
                float rs = rsqrtf(s2 * (1.0f / 32.0f) + 1e-5f);
                float y = dd * rs * ang + anb;
                float sl = 0.6f * y + 0.4f * y * (2.0f * sigf(y) - 1.0f);
                float lgv = sl * ad;
#pragma unroll
                for (int m = 1; m < 32; m <<= 1) lgv += __shfl_xor(lgv, m, 32);
                if (s == 0) lgS[e][h] = maskk[e] ? -1e9f : lgv;
            }
        }
    }
    __syncthreads();

    // ===== softmax over k, write alpha =====
    if (t < 8) {
        float mx = -1e30f;
#pragma unroll
        for (int k = 0; k < 32; ++k) mx = fmaxf(mx, lgS[k][t]);
        float sum = 0.0f;
#pragma unroll
        for (int k = 0; k < 32; ++k) sum += __expf(lgS[k][t] - mx);
        mxS[t] = mx;
        invS[t] = 1.0f / sum;
    }
    __syncthreads();
    {
        int k = t >> 3, h = t & 7;
        al_g[(size_t)n * 256 + t] = __expf(lgS[k][h] - mxS[h]) * invS[h];
    }
}

// ---------------- K2c: gather + aggregate (latency-bound, high-occupancy) --------
__global__ __launch_bounds__(256) void k2c(
    const float* __restrict__ al_g, const float* __restrict__ h2v_g,
    const int* __restrict__ f_idx, const unsigned short* __restrict__ clh,
    const float* __restrict__ rv_w3, const float* __restrict__ rv_b3,
    float* __restrict__ outpre)
{
    __shared__ float alS[256];        // [k][8]
    __shared__ float h2S[32][16];
    __shared__ int idxS[32];
    int n = blockIdx.x, t = threadIdx.x;
    alS[t] = al_g[(size_t)n * 256 + t];
    if (t < 32) idxS[t] = f_idx[n * KNBR + t];
    for (int i = t; i < 512; i += 256) h2S[i >> 4][i & 15] = h2v_g[(size_t)n * 512 + i];
    __syncthreads();

    int c = t, h = c >> 5;
    // av[k] = alpha[k][h] * vw[k][c]
    float avr[32];
    {
        float w3r[16];
        const float4* w3p = (const float4*)(rv_w3 + c * 16);
#pragma unroll
        for (int i4 = 0; i4 < 4; ++i4) {
            float4 w = w3p[i4];
            w3r[i4 * 4 + 0] = w.x; w3r[i4 * 4 + 1] = w.y;
            w3r[i4 * 4 + 2] = w.z; w3r[i4 * 4 + 3] = w.w;
        }
        float b3c = rv_b3[c];
#pragma unroll
        for (int k = 0; k < 32; ++k) {
            float vw = b3c;
#pragma unroll
            for (int i = 0; i < 16; ++i) vw = fmaf(h2S[k][i], w3r[i], vw);
            avr[k] = alS[k * 8 + h] * vw;
        }
    }

    float acc[9];
#pragma unroll
    for (int m = 0; m < 9; ++m) acc[m] = 0.0f;
#pragma unroll 4
    for (int k = 0; k < 32; ++k) {
        const unsigned short* crow = clh + (size_t)idxS[k] * 2304 + c;
        float av = avr[k];
#pragma unroll
        for (int m = 0; m < 9; ++m) acc[m] = fmaf(av, bf2f(crow[m * 256]), acc[m]);
    }
#pragma unroll
    for (int m = 0; m < 9; ++m) outpre[((size_t)n * 9 + m) * 256 + c] = acc[m];
}

// ---------------- K5: final so3_linear with wz (+bz on l=0), in-place on d_out ----
__global__ __launch_bounds__(256) void k5_final(
    const float* __restrict__ wz, const float* __restrict__ bz,
    float* __restrict__ io)
{
    __shared__ __align__(16) float X[32][256];
    __shared__ int rr[32];
    int b = blockIdx.x, t = threadIdx.x;
    int l, vr0, nm, moff;
    if (b < 64)       { l = 0; vr0 = b * 32;         nm = 1; moff = 0; }
    else if (b < 256) { l = 1; vr0 = (b - 64) * 32;  nm = 3; moff = 1; }
    else              { l = 2; vr0 = (b - 256) * 32; nm = 5; moff = 4; }
    if (t < 32) {
        int vr = vr0 + t;
        int n = vr / nm, m = moff + vr % nm;
        rr[t] = n * 9 + m;
    }
    __syncthreads();
    for (int e = t; e < 32 * 256; e += 256) {
        int r = e >> 8, c = e & 255;
        X[r][c] = io[(size_t)rr[r] * 256 + c];
    }
    __syncthreads();
    int d = t;
    float acc[32];
    float bias = (l == 0) ? bz[d] : 0.0f;
#pragma unroll
    for (int r = 0; r < 32; ++r) acc[r] = bias;
    const float4* w = (const float4*)(wz + ((size_t)l * 256 + d) * 256);
    for (int c4 = 0; c4 < 64; ++c4) {
        float4 wv = w[c4];
#pragma unroll
        for (int r = 0; r < 32; ++r) {
            float4 x4 = *(const float4*)&X[r][c4 * 4];
            acc[r] = fmaf(x4.x, wv.x, fmaf(x4.y, wv.y, fmaf(x4.z, wv.z, fmaf(x4.w, wv.w, acc[r]))));
        }
    }
#pragma unroll
    for (int r = 0; r < 32; ++r) io[(size_t)rr[r] * 256 + d] = acc[r];
}

// ---------------- launch ----------------
extern "C" void kernel_launch(void* const* d_in, const int* in_sizes, int n_in,
                              void* d_out, int out_size, void* d_ws, size_t ws_size,
                              hipStream_t stream)
{
    (void)in_sizes; (void)n_in; (void)out_size; (void)ws_size;

    const float* node_irreps = (const float*)d_in[1];
    const float* edge_vec    = (const float*)d_in[3];
    const float* attn_weight = (const float*)d_in[4];
    const int*   atom_num    = (const int*)d_in[5];
    const void*  attn_mask   = d_in[6];
    const int*   f_idx       = (const int*)d_in[7];
    const float* clus        = (const float*)d_in[8];
    const float* tgt_emb     = (const float*)d_in[9];
    const float* W_dot       = (const float*)d_in[10];
    const float* b_dot       = (const float*)d_in[11];
    const float* rm0_w1 = (const float*)d_in[12];
    const float* rm0_b1 = (const float*)d_in[13];
    const float* rm0_g1 = (const float*)d_in[14];
    const float* rm0_be1 = (const float*)d_in[15];
    const float* rm0_w2 = (const float*)d_in[16];
    const float* rm0_b2 = (const float*)d_in[17];
    const float* rm0_g2 = (const float*)d_in[18];
    const float* rm0_be2 = (const float*)d_in[19];
    const float* rm0_w3 = (const float*)d_in[20];
    const float* rm0_b3 = (const float*)d_in[21];
    const float* fcw = (const float*)d_in[22];
    const float* fcb = (const float*)d_in[23];
    const float* an_g = (const float*)d_in[24];
    const float* an_b = (const float*)d_in[25];
    const float* alpha_dot = (const float*)d_in[26];
    const float* rv_w1 = (const float*)d_in[27];
    const float* rv_b1 = (const float*)d_in[28];
    const float* rv_g1 = (const float*)d_in[29];
    const float* rv_be1 = (const float*)d_in[30];
    const float* rv_w2 = (const float*)d_in[31];
    const float* rv_b2 = (const float*)d_in[32];
    const float* rv_g2 = (const float*)d_in[33];
    const float* rv_be2 = (const float*)d_in[34];
    const float* rv_w3 = (const float*)d_in[35];
    const float* rv_b3 = (const float*)d_in[36];
    const float* wz = (const float*)d_in[37];
    const float* bz = (const float*)d_in[38];

    float* ws = (float*)d_ws;
    int* flag = (int*)d_ws;
    float* q_ws = ws + 16;                                                   // 2048*288 f32
    unsigned short* keyh = (unsigned short*)(q_ws + (size_t)NNODE * 288);    // 2048*288 bf16
    float* TA_ws = (float*)(keyh + (size_t)MCLUS * 288);                     // 256*32
    float* CA_ws = TA_ws + 256 * 32;                                         // 2048*32
    unsigned short* clh = (unsigned short*)(CA_ws + (size_t)MCLUS * 32);     // 2048*2304 bf16
    float* al_ws = (float*)(clh + (size_t)MCLUS * 2304);                     // 2048*256
    float* h2v_ws = al_ws + (size_t)NNODE * 256;                             // 2048*512
    float* outpre = (float*)d_out;

    hipMemsetAsync(flag, 0, sizeof(int), stream);
    k0_detect<<<64, 256, 0, stream>>>((const unsigned int*)attn_mask, flag);
    kconv<<<MCLUS, 256, 0, stream>>>(clus, clh);
    kpre<<<288, 256, 0, stream>>>(tgt_emb, clus, rm0_w1, rv_w1, TA_ws, CA_ws);
    k1_so3qk<<<1152, 256, 0, stream>>>(node_irreps, clus, W_dot, b_dot, q_ws, keyh);
    k2ab<<<NNODE, 256, 0, stream>>>(
        attn_weight, attn_mask, flag, f_idx, edge_vec, atom_num,
        q_ws, keyh, TA_ws, CA_ws,
        rm0_w1, rm0_b1, rm0_g1, rm0_be1, rm0_w2, rm0_b2, rm0_g2, rm0_be2, rm0_w3, rm0_b3,
        fcw, fcb, an_g, an_b, alpha_dot,
        rv_w1, rv_b1, rv_g1, rv_be1, rv_w2, rv_b2, rv_g2, rv_be2,
        al_ws, h2v_ws);
    k2c<<<NNODE, 256, 0, stream>>>(al_ws, h2v_ws, f_idx, clh, rv_w3, rv_b3, outpre);
    k5_final<<<576, 256, 0, stream>>>(wz, bz, outpre);
}

// Round 7
// 636.206 us; speedup vs baseline: 1.5874x; 1.0303x over previous
//
#include <hip/hip_runtime.h>
#include <math.h>

#define NNODE 2048
#define MCLUS 2048
#define KNBR  32
#define CDIM  256
#define HHEAD 8

__device__ __forceinline__ float sigf(float x) { return 1.0f / (1.0f + __expf(-x)); }

__device__ __forceinline__ unsigned short f2bf(float f) {
    unsigned x = __float_as_uint(f);
    unsigned r = ((x >> 16) & 1u) + 0x7FFFu;
    return (unsigned short)((x + r) >> 16);
}
__device__ __forceinline__ float bf2f(unsigned short u) {
    return __uint_as_float(((unsigned)u) << 16);
}

// ---------------- K0: detect attn_mask storage layout ----------------
__global__ void k0_detect(const unsigned int* __restrict__ mw, int* __restrict__ flag) {
    int i = blockIdx.x * blockDim.x + threadIdx.x;
    unsigned int w = mw[i];
    int vb = (w != 0u && w != 1u && w != 0x3F800000u) ? 1 : 0;
    int vf = (w == 0x3F800000u) ? 1 : 0;
    unsigned long long bal_b = __ballot(vb);
    unsigned long long bal_f = __ballot(vf);
    if ((threadIdx.x & 63) == 0) {
        if (bal_b) atomicOr(flag, 1);
        if (bal_f) atomicOr(flag, 2);
    }
}

__device__ __forceinline__ bool edge_masked(const void* mp, int mode, int e) {
    if (mode & 2) return ((const float*)mp)[e] != 0.0f;
    if (mode & 1) return ((const unsigned char*)mp)[e] != 0;
    return ((const int*)mp)[e] != 0;
}

// ---------------- Kconv: clus fp32 -> bf16 copy ----------------
__global__ __launch_bounds__(256) void kconv(const float* __restrict__ clus,
                                             unsigned short* __restrict__ clh) {
    size_t base = (size_t)blockIdx.x * 2304;
    int t = threadIdx.x;
#pragma unroll
    for (int r = 0; r < 9; ++r) {
        int o = r * 256 + t;
        clh[base + o] = f2bf(clus[base + o]);
    }
}

// ---------------- Kpre: fold tgt/cl_scal parts of radial layer-1 ----------------
__global__ __launch_bounds__(256) void kpre(
    const float* __restrict__ tgt_emb, const float* __restrict__ clus,
    const float* __restrict__ rm0_w1, const float* __restrict__ rv_w1,
    float* __restrict__ TA, float* __restrict__ CA)
{
    int b = blockIdx.x, t = threadIdx.x;
    int slot = t & 31, j = slot & 15, mlp = slot >> 4;
    const float* w1 = mlp ? rv_w1 : rm0_w1;
    if (b < 32) {
        int a = b * 8 + (t >> 5);
        const float* x = tgt_emb + (size_t)a * 128;
        const float* w = w1 + j * 416 + 32;
        float acc = 0.0f;
        for (int i = 0; i < 128; i += 4)
            acc = fmaf(x[i], w[i], fmaf(x[i+1], w[i+1], fmaf(x[i+2], w[i+2], fmaf(x[i+3], w[i+3], acc))));
        TA[a * 32 + slot] = acc;
    } else {
        int m = (b - 32) * 8 + (t >> 5);
        const float* x = clus + (size_t)m * 2304;
        const float* w = w1 + j * 416 + 160;
        float acc = 0.0f;
        for (int i = 0; i < 256; i += 4)
            acc = fmaf(x[i], w[i], fmaf(x[i+1], w[i+1], fmaf(x[i+2], w[i+2], fmaf(x[i+3], w[i+3], acc))));
        CA[m * 32 + slot] = acc;
    }
}

// ---------------- K1: so3_linear; q (fp32) for nodes, key (bf16) for clusters ----
__global__ __launch_bounds__(256) void k1_so3qk(
    const float* __restrict__ nodei, const float* __restrict__ clus,
    const float* __restrict__ W_dot, const float* __restrict__ b_dot,
    float* __restrict__ q_ws, unsigned short* __restrict__ keyh)
{
    __shared__ __align__(16) float X[32][256];
    __shared__ int rx[32], rmm[32];
    int b = blockIdx.x, t = threadIdx.x;
    int l, vr0, nm, moff;
    if (b < 128)      { l = 0; vr0 = b * 32;         nm = 1; moff = 0; }
    else if (b < 512) { l = 1; vr0 = (b - 128) * 32; nm = 3; moff = 1; }
    else              { l = 2; vr0 = (b - 512) * 32; nm = 5; moff = 4; }
    if (t < 32) {
        int vr = vr0 + t;
        rx[t] = vr / nm;
        rmm[t] = moff + vr % nm;
    }
    __syncthreads();
    for (int e = t; e < 32 * 256; e += 256) {
        int r = e >> 8, c = e & 255;
        int x = rx[r], m = rmm[r];
        const float* src = (x < NNODE) ? (nodei + ((size_t)x * 9 + m) * 256)
                                       : (clus + ((size_t)(x - NNODE) * 9 + m) * 256);
        X[r][c] = src[c];
    }
    __syncthreads();
    int d = t & 31, rg = t >> 5;
    int r0 = rg * 4;
    const float4* wrow = (const float4*)(W_dot + ((size_t)l * 32 + d) * 256);
    float acc[4];
    float bd = (l == 0) ? b_dot[d] : 0.0f;
#pragma unroll
    for (int jj = 0; jj < 4; ++jj) acc[jj] = bd;
    for (int c4 = 0; c4 < 64; ++c4) {
        float4 w = wrow[c4];
#pragma unroll
        for (int jj = 0; jj < 4; ++jj) {
            float4 x4 = *(const float4*)&X[r0 + jj][c4 * 4];
            acc[jj] = fmaf(x4.x, w.x, fmaf(x4.y, w.y, fmaf(x4.z, w.z, fmaf(x4.w, w.w, acc[jj]))));
        }
    }
#pragma unroll
    for (int jj = 0; jj < 4; ++jj) {
        int r = r0 + jj;
        int x = rx[r], m = rmm[r];
        if (x < NNODE) q_ws[((size_t)x * 9 + m) * 32 + d] = acc[jj];
        else           keyh[((size_t)(x - NNODE) * 9 + m) * 32 + d] = f2bf(acc[jj]);
    }
}

// ---------------- K2ab: edge MLPs + logits + softmax (compute-bound) -------------
__device__ __forceinline__ float lnsilu16(float x, float g, float b) {
    float s = x;
#pragma unroll
    for (int m = 1; m < 16; m <<= 1) s += __shfl_xor(s, m, 16);
    float mu = s * 0.0625f;
    float d = x - mu;
    float s2 = d * d;
#pragma unroll
    for (int m = 1; m < 16; m <<= 1) s2 += __shfl_xor(s2, m, 16);
    float y = d * rsqrtf(s2 * 0.0625f + 1e-5f) * g + b;
    return y * sigf(y);
}

__global__ __launch_bounds__(256, 2) void k2ab(
    const float* __restrict__ attn_weight, const void* __restrict__ mask,
    const int* __restrict__ mflag,
    const int* __restrict__ f_idx, const float* __restrict__ edge_vec,
    const int* __restrict__ atom_num,
    const float* __restrict__ q_ws, const unsigned short* __restrict__ keyh,
    const float* __restrict__ TA, const float* __restrict__ CA,
    const float* __restrict__ rm0_w1, const float* __restrict__ rm0_b1,
    const float* __restrict__ rm0_g1, const float* __restrict__ rm0_be1,
    const float* __restrict__ rm0_w2, const float* __restrict__ rm0_b2,
    const float* __restrict__ rm0_g2, const float* __restrict__ rm0_be2,
    const float* __restrict__ rm0_w3, const float* __restrict__ rm0_b3,
    const float* __restrict__ fcw, const float* __restrict__ fcb,
    const float* __restrict__ an_g, const float* __restrict__ an_b,
    const float* __restrict__ alpha_dot,
    const float* __restrict__ rv_w1, const float* __restrict__ rv_b1,
    const float* __restrict__ rv_g1, const float* __restrict__ rv_be1,
    const float* __restrict__ rv_w2, const float* __restrict__ rv_b2,
    const float* __restrict__ rv_g2, const float* __restrict__ rv_be2,
    float* __restrict__ al_g, float* __restrict__ h2v_g)
{
    __shared__ float qn[288];
    __shared__ float Ts[32];
    __shared__ float shS[32][9];
    __shared__ float awS[32][32];
    __shared__ float caS[32][32];
    __shared__ __align__(16) float mwaS[32][196];
    __shared__ float lgS[32][8];
    __shared__ float mxS[8], invS[8];
    __shared__ int idxk[32], maskk[32];

    int n = blockIdx.x, t = threadIdx.x;
    int mode = mflag[0];

    for (int i = t; i < 288; i += 256) qn[i] = q_ws[(size_t)n * 288 + i];
    if (t < 32) {
        int an = atom_num[n];
        Ts[t] = TA[an * 32 + t];
        int e = n * KNBR + t;
        idxk[t] = f_idx[e];
        maskk[t] = edge_masked(mask, mode, e) ? 1 : 0;
        float vx = edge_vec[(size_t)e * 3 + 0];
        float vy = edge_vec[(size_t)e * 3 + 1];
        float vz = edge_vec[(size_t)e * 3 + 2];
        float inv = 1.0f / (sqrtf(vx * vx + vy * vy + vz * vz) + 1e-12f);
        float x = vx * inv, y = vy * inv, z = vz * inv;
        shS[t][0] = 0.28209479177387814f;
        shS[t][1] = 0.4886025119029199f * y;
        shS[t][2] = 0.4886025119029199f * z;
        shS[t][3] = 0.4886025119029199f * x;
        shS[t][4] = 1.0925484305920792f * x * y;
        shS[t][5] = 1.0925484305920792f * y * z;
        shS[t][6] = 0.31539156525252005f * (3.0f * z * z - 1.0f);
        shS[t][7] = 1.0925484305920792f * x * z;
        shS[t][8] = 0.5462742152960396f * (x * x - y * y);
    }
    __syncthreads();
    for (int e2 = t; e2 < 1024; e2 += 256) {
        int ek = e2 >> 5, i = e2 & 31;
        awS[ek][i] = maskk[ek] ? 0.0f : attn_weight[((size_t)(n * KNBR + ek)) * 32 + i];
        caS[ek][i] = CA[(size_t)idxk[ek] * 32 + i];
    }
    __syncthreads();

    // ===== phase A: edge MLPs (wave-parallel, 16-lane groups) =====
    {
        int g = t >> 4, j = t & 15;
        for (int ee = 0; ee < 2; ++ee) {
            int e = g + ee * 16;
            int idx = idxk[e];
            float accm = rm0_b1[j] + Ts[j] + caS[e][j];
            float accv = rv_b1[j] + Ts[16 + j] + caS[e][16 + j];
            const float* w1m = rm0_w1 + j * 416;
            const float* w1v = rv_w1 + j * 416;
#pragma unroll
            for (int i = 0; i < 32; i += 4) {
                float a0 = awS[e][i], a1 = awS[e][i + 1], a2 = awS[e][i + 2], a3 = awS[e][i + 3];
                accm = fmaf(a0, w1m[i], fmaf(a1, w1m[i+1], fmaf(a2, w1m[i+2], fmaf(a3, w1m[i+3], accm))));
                accv = fmaf(a0, w1v[i], fmaf(a1, w1v[i+1], fmaf(a2, w1v[i+2], fmaf(a3, w1v[i+3], accv))));
            }
            float hm = lnsilu16(accm, rm0_g1[j], rm0_be1[j]);
            float hv = lnsilu16(accv, rv_g1[j], rv_be1[j]);
            float am2 = rm0_b2[j], av2 = rv_b2[j];
#pragma unroll
            for (int i = 0; i < 16; ++i) {
                am2 = fmaf(__shfl(hm, i, 16), rm0_w2[j * 16 + i], am2);
                av2 = fmaf(__shfl(hv, i, 16), rv_w2[j * 16 + i], av2);
            }
            float h2m = lnsilu16(am2, rm0_g2[j], rm0_be2[j]);
            float h2v = lnsilu16(av2, rv_g2[j], rv_be2[j]);
            h2v_g[(size_t)n * 512 + e * 16 + j] = h2v;

            const unsigned short* keyrow = keyh + (size_t)idx * 288;
            float h16[16];
#pragma unroll
            for (int i = 0; i < 16; ++i) h16[i] = __shfl(h2m, i, 16);
#pragma unroll
            for (int r = 0; r < 12; ++r) {
                int d = r * 16 + j;
                const float* w3 = rm0_w3 + d * 16;
                float ew = rm0_b3[d];
#pragma unroll
                for (int i = 0; i < 16; ++i) ew = fmaf(h16[i], w3[i], ew);
                int c = ((r & 1) << 4) + j;   // d & 31
                int bb = r >> 1;              // d >> 5
                float m0v;
                if (bb == 0)      m0v = qn[c] * shS[e][0];
                else if (bb == 1) m0v = qn[32 + c] * shS[e][1] + qn[64 + c] * shS[e][2]
                                      + qn[96 + c] * shS[e][3];
                else if (bb == 2) m0v = qn[128 + c] * shS[e][4] + qn[160 + c] * shS[e][5]
                                      + qn[192 + c] * shS[e][6] + qn[224 + c] * shS[e][7]
                                      + qn[256 + c] * shS[e][8];
                else if (bb == 3) m0v = bf2f(keyrow[c]) * shS[e][0];
                else if (bb == 4) m0v = bf2f(keyrow[32 + c]) * shS[e][1]
                                      + bf2f(keyrow[64 + c]) * shS[e][2]
                                      + bf2f(keyrow[96 + c]) * shS[e][3];
                else              m0v = bf2f(keyrow[128 + c]) * shS[e][4]
                                      + bf2f(keyrow[160 + c]) * shS[e][5]
                                      + bf2f(keyrow[192 + c]) * shS[e][6]
                                      + bf2f(keyrow[224 + c]) * shS[e][7]
                                      + bf2f(keyrow[256 + c]) * shS[e][8];
                mwaS[e][d] = ew * m0v;
            }
        }
    }
    __syncthreads();

    // ===== phase B1: af GEMM, single fcw pass, acc over all 32 edges =====
    // afS overlays columns 192..195 unused? No: store af into lgS path via LDS afS.
    {
        float acc[32];
        float bias = fcb[t];
#pragma unroll
        for (int e = 0; e < 32; ++e) acc[e] = bias;
        const float4* fr = (const float4*)(fcw + (size_t)t * 192);
        for (int i4 = 0; i4 < 48; ++i4) {
            float4 wv = fr[i4];
#pragma unroll
            for (int e = 0; e < 32; ++e) {
                float4 m4 = *(const float4*)&mwaS[e][i4 * 4];
                acc[e] = fmaf(m4.x, wv.x, fmaf(m4.y, wv.y, fmaf(m4.z, wv.z, fmaf(m4.w, wv.w, acc[e]))));
            }
        }
        // ===== phase B2: LN + smooth_leaky + logits (lane-parallel over s) =====
        int h = t >> 5, s = t & 31;
        float ang = an_g[s], anb = an_b[s], ad = alpha_dot[h * 32 + s];
#pragma unroll
        for (int e = 0; e < 32; ++e) {
            float v = acc[e];
            float su = v;
#pragma unroll
            for (int m = 1; m < 32; m <<= 1) su += __shfl_xor(su, m, 32);
            float mu = su * (1.0f / 32.0f);
            float dd = v - mu;
            float s2 = dd * dd;
#pragma unroll
            for (int m = 1; m < 32; m <<= 1) s2 += __shfl_xor(s2, m, 32);
            float rs = rsqrtf(s2 * (1.0f / 32.0f) + 1e-5f);
            float y = dd * rs * ang + anb;
            float sl = 0.6f * y + 0.4f * y * (2.0f * sigf(y) - 1.0f);
            float lgv = sl * ad;
#pragma unroll
            for (int m = 1; m < 32; m <<= 1) lgv += __shfl_xor(lgv, m, 32);
            if (s == 0) lgS[e][h] = maskk[e] ? -1e9f : lgv;
        }
    }
    __syncthreads();

    // ===== softmax over k, write alpha =====
    if (t < 8) {
        float mx = -1e30f;
#pragma unroll
        for (int k = 0; k < 32; ++k) mx = fmaxf(mx, lgS[k][t]);
        float sum = 0.0f;
#pragma unroll
        for (int k = 0; k < 32; ++k) sum += __expf(lgS[k][t] - mx);
        mxS[t] = mx;
        invS[t] = 1.0f / sum;
    }
    __syncthreads();
    {
        int k = t >> 3, h = t & 7;
        al_g[(size_t)n * 256 + t] = __expf(lgS[k][h] - mxS[h]) * invS[h];
    }
}

// ---------------- K2c: gather + aggregate (latency-bound, high-occupancy) --------
__global__ __launch_bounds__(256) void k2c(
    const float* __restrict__ al_g, const float* __restrict__ h2v_g,
    const int* __restrict__ f_idx, const unsigned short* __restrict__ clh,
    const float* __restrict__ rv_w3, const float* __restrict__ rv_b3,
    float* __restrict__ outpre)
{
    __shared__ float alS[256];        // [k][8]
    __shared__ float h2S[32][16];
    __shared__ int idxS[32];
    int n = blockIdx.x, t = threadIdx.x;
    alS[t] = al_g[(size_t)n * 256 + t];
    if (t < 32) idxS[t] = f_idx[n * KNBR + t];
    for (int i = t; i < 512; i += 256) h2S[i >> 4][i & 15] = h2v_g[(size_t)n * 512 + i];
    __syncthreads();

    int c = t, h = c >> 5;
    float avr[32];
    {
        float w3r[16];
        const float4* w3p = (const float4*)(rv_w3 + c * 16);
#pragma unroll
        for (int i4 = 0; i4 < 4; ++i4) {
            float4 w = w3p[i4];
            w3r[i4 * 4 + 0] = w.x; w3r[i4 * 4 + 1] = w.y;
            w3r[i4 * 4 + 2] = w.z; w3r[i4 * 4 + 3] = w.w;
        }
        float b3c = rv_b3[c];
#pragma unroll
        for (int k = 0; k < 32; ++k) {
            float vw = b3c;
#pragma unroll
            for (int i = 0; i < 16; ++i) vw = fmaf(h2S[k][i], w3r[i], vw);
            avr[k] = alS[k * 8 + h] * vw;
        }
    }

    float acc[9];
#pragma unroll
    for (int m = 0; m < 9; ++m) acc[m] = 0.0f;
#pragma unroll 4
    for (int k = 0; k < 32; ++k) {
        const unsigned short* crow = clh + (size_t)idxS[k] * 2304 + c;
        float av = avr[k];
#pragma unroll
        for (int m = 0; m < 9; ++m) acc[m] = fmaf(av, bf2f(crow[m * 256]), acc[m]);
    }
#pragma unroll
    for (int m = 0; m < 9; ++m) outpre[((size_t)n * 9 + m) * 256 + c] = acc[m];
}

// ---------------- K5: final so3_linear with wz (+bz on l=0), in-place on d_out ----
__global__ __launch_bounds__(256) void k5_final(
    const float* __restrict__ wz, const float* __restrict__ bz,
    float* __restrict__ io)
{
    __shared__ __align__(16) float X[32][256];
    __shared__ int rr[32];
    int b = blockIdx.x, t = threadIdx.x;
    int l, vr0, nm, moff;
    if (b < 64)       { l = 0; vr0 = b * 32;         nm = 1; moff = 0; }
    else if (b < 256) { l = 1; vr0 = (b - 64) * 32;  nm = 3; moff = 1; }
    else              { l = 2; vr0 = (b - 256) * 32; nm = 5; moff = 4; }
    if (t < 32) {
        int vr = vr0 + t;
        int n = vr / nm, m = moff + vr % nm;
        rr[t] = n * 9 + m;
    }
    __syncthreads();
    for (int e = t; e < 32 * 256; e += 256) {
        int r = e >> 8, c = e & 255;
        X[r][c] = io[(size_t)rr[r] * 256 + c];
    }
    __syncthreads();
    int d = t;
    float acc[32];
    float bias = (l == 0) ? bz[d] : 0.0f;
#pragma unroll
    for (int r = 0; r < 32; ++r) acc[r] = bias;
    const float4* w = (const float4*)(wz + ((size_t)l * 256 + d) * 256);
    for (int c4 = 0; c4 < 64; ++c4) {
        float4 wv = w[c4];
#pragma unroll
        for (int r = 0; r < 32; ++r) {
            float4 x4 = *(const float4*)&X[r][c4 * 4];
            acc[r] = fmaf(x4.x, wv.x, fmaf(x4.y, wv.y, fmaf(x4.z, wv.z, fmaf(x4.w, wv.w, acc[r]))));
        }
    }
#pragma unroll
    for (int r = 0; r < 32; ++r) io[(size_t)rr[r] * 256 + d] = acc[r];
}

// ---------------- launch ----------------
extern "C" void kernel_launch(void* const* d_in, const int* in_sizes, int n_in,
                              void* d_out, int out_size, void* d_ws, size_t ws_size,
                              hipStream_t stream)
{
    (void)in_sizes; (void)n_in; (void)out_size; (void)ws_size;

    const float* node_irreps = (const float*)d_in[1];
    const float* edge_vec    = (const float*)d_in[3];
    const float* attn_weight = (const float*)d_in[4];
    const int*   atom_num    = (const int*)d_in[5];
    const void*  attn_mask   = d_in[6];
    const int*   f_idx       = (const int*)d_in[7];
    const float* clus        = (const float*)d_in[8];
    const float* tgt_emb     = (const float*)d_in[9];
    const float* W_dot       = (const float*)d_in[10];
    const float* b_dot       = (const float*)d_in[11];
    const float* rm0_w1 = (const float*)d_in[12];
    const float* rm0_b1 = (const float*)d_in[13];
    const float* rm0_g1 = (const float*)d_in[14];
    const float* rm0_be1 = (const float*)d_in[15];
    const float* rm0_w2 = (const float*)d_in[16];
    const float* rm0_b2 = (const float*)d_in[17];
    const float* rm0_g2 = (const float*)d_in[18];
    const float* rm0_be2 = (const float*)d_in[19];
    const float* rm0_w3 = (const float*)d_in[20];
    const float* rm0_b3 = (const float*)d_in[21];
    const float* fcw = (const float*)d_in[22];
    const float* fcb = (const float*)d_in[23];
    const float* an_g = (const float*)d_in[24];
    const float* an_b = (const float*)d_in[25];
    const float* alpha_dot = (const float*)d_in[26];
    const float* rv_w1 = (const float*)d_in[27];
    const float* rv_b1 = (const float*)d_in[28];
    const float* rv_g1 = (const float*)d_in[29];
    const float* rv_be1 = (const float*)d_in[30];
    const float* rv_w2 = (const float*)d_in[31];
    const float* rv_b2 = (const float*)d_in[32];
    const float* rv_g2 = (const float*)d_in[33];
    const float* rv_be2 = (const float*)d_in[34];
    const float* rv_w3 = (const float*)d_in[35];
    const float* rv_b3 = (const float*)d_in[36];
    const float* wz = (const float*)d_in[37];
    const float* bz = (const float*)d_in[38];

    float* ws = (float*)d_ws;
    int* flag = (int*)d_ws;
    float* q_ws = ws + 16;                                                   // 2048*288 f32
    unsigned short* keyh = (unsigned short*)(q_ws + (size_t)NNODE * 288);    // 2048*288 bf16
    float* TA_ws = (float*)(keyh + (size_t)MCLUS * 288);                     // 256*32
    float* CA_ws = TA_ws + 256 * 32;                                         // 2048*32
    unsigned short* clh = (unsigned short*)(CA_ws + (size_t)MCLUS * 32);     // 2048*2304 bf16
    float* al_ws = (float*)(clh + (size_t)MCLUS * 2304);                     // 2048*256
    float* h2v_ws = al_ws + (size_t)NNODE * 256;                             // 2048*512
    float* outpre = (float*)d_out;

    hipMemsetAsync(flag, 0, sizeof(int), stream);
    k0_detect<<<64, 256, 0, stream>>>((const unsigned int*)attn_mask, flag);
    kconv<<<MCLUS, 256, 0, stream>>>(clus, clh);
    kpre<<<288, 256, 0, stream>>>(tgt_emb, clus, rm0_w1, rv_w1, TA_ws, CA_ws);
    k1_so3qk<<<1152, 256, 0, stream>>>(node_irreps, clus, W_dot, b_dot, q_ws, keyh);
    k2ab<<<NNODE, 256, 0, stream>>>(
        attn_weight, attn_mask, flag, f_idx, edge_vec, atom_num,
        q_ws, keyh, TA_ws, CA_ws,
        rm0_w1, rm0_b1, rm0_g1, rm0_be1, rm0_w2, rm0_b2, rm0_g2, rm0_be2, rm0_w3, rm0_b3,
        fcw, fcb, an_g, an_b, alpha_dot,
        rv_w1, rv_b1, rv_g1, rv_be1, rv_w2, rv_b2, rv_g2, rv_be2,
        al_ws, h2v_ws);
    k2c<<<NNODE, 256, 0, stream>>>(al_ws, h2v_ws, f_idx, clh, rv_w3, rv_b3, outpre);
    k5_final<<<576, 256, 0, stream>>>(wz, bz, outpre);
}